// Round 3
// baseline (195.101 us; speedup 1.0000x reference)
//
#include <hip/hip_runtime.h>

// MoreParamDenseQConv1D: quantum-circuit conv1d.
// B=16, C_in=4, L=2048, K=8, OUT_CH=8, N_LAYERS=2, N_QUBITS=7, DIM=128.
// One wave evolves NS=4 independent (row, oc) 128-dim complex states
// (2 complex amps per lane per state) for 4-way ILP. The acting qubit is
// kept in the "slot" axis via slot<->lane-bit re-pairings:
//   m=32 -> v_permlane32_swap_b32 (1 VALU instr per register)
//   m=16 -> v_permlane16_swap_b32
//   m<=8 -> ds_bpermute + cndmask
// so every gate is an in-lane 16-FMA complex 2x2 matvec with wave-uniform
// (SGPR) coefficients.

#define L_OUT 2041
#define N_ROWS (16 * L_OUT)   // 32656
#define NS 4
#define N_BLK (N_ROWS / NS)   // 8164 blocks x 8 waves

__device__ __forceinline__ float bperm(int addr, float v) {
    return __int_as_float(__builtin_amdgcn_ds_bpermute(addr, __float_as_int(v)));
}

// Per gate 4 floats: u00r, u00i, u10r, u10i.
// u00 = conj(ep)*cb, u10 = em*sb, u01 = -conj(u10), u11 = conj(u00).
__device__ __forceinline__ void gate_coeffs(const float* __restrict__ thetas, int i,
                                            float* o) {
    float a = thetas[i * 3 + 0], b = thetas[i * 3 + 1], g = thetas[i * 3 + 2];
    float sb = sinf(b * 0.5f), cb = cosf(b * 0.5f);
    float sp, cp, sm, cm;
    sincosf((a + g) * 0.5f, &sp, &cp);
    sincosf((a - g) * 0.5f, &sm, &cm);
    o[0] = cp * cb;
    o[1] = -sp * cb;
    o[2] = cm * sb;
    o[3] = sm * sb;
}

__global__ void prep_gates_k(const float* __restrict__ thetas, float* __restrict__ gates) {
    int i = threadIdx.x;
    if (i >= 112) return;  // i = oc*14 + l*7 + q
    float o[4];
    gate_coeffs(thetas, i, o);
    gates[i * 4 + 0] = o[0];
    gates[i * 4 + 1] = o[1];
    gates[i * 4 + 2] = o[2];
    gates[i * 4 + 3] = o[3];
}

template <bool USE_WS>
__global__ __launch_bounds__(512) void qconv_k(const float* __restrict__ x,
                                               const float* __restrict__ thetas,
                                               const float* __restrict__ gates_g,
                                               float* __restrict__ out) {
    int lane = threadIdx.x & 63;
    int oc = __builtin_amdgcn_readfirstlane(threadIdx.x >> 6);  // 0..7

    const float* gb;
    __shared__ float gl[112 * 4];
    if constexpr (!USE_WS) {
        int t = threadIdx.x;
        if (t < 112) {
            float o[4];
            gate_coeffs(thetas, t, o);
            gl[t * 4 + 0] = o[0];
            gl[t * 4 + 1] = o[1];
            gl[t * 4 + 2] = o[2];
            gl[t * 4 + 3] = o[3];
        }
        __syncthreads();
        gb = gl + oc * 56;
    } else {
        gb = gates_g + oc * 56;  // 14 gates * 4 floats, wave-uniform
    }

    // Preload all 14 gate quads (uniform -> SGPRs, no mid-chain loads).
    float gc[56];
#pragma unroll
    for (int i = 0; i < 14; ++i) {
        float4 gg = *(const float4*)(gb + i * 4);
        gc[i * 4 + 0] = gg.x;
        gc[i * 4 + 1] = gg.y;
        gc[i * 4 + 2] = gg.z;
        gc[i * 4 + 3] = gg.w;
    }

    int row0 = blockIdx.x * NS;
    int bidx[NS], lidx[NS];
    float xv[NS];
#pragma unroll
    for (int s = 0; s < NS; ++s) {
        int row = row0 + s;
        int b = row / L_OUT;
        bidx[s] = b;
        lidx[s] = row - b * L_OUT;
        float t = 0.f;
        if (lane < 32) {
            int c = lane >> 3, k = lane & 7;
            t = x[(b * 4 + c) * 2048 + lidx[s] + k];
        }
        xv[s] = t;
    }

    // norm: sum of squares over the wave (interleaved across states)
    float acc[NS];
#pragma unroll
    for (int s = 0; s < NS; ++s) acc[s] = xv[s] * xv[s];
#pragma unroll
    for (int m = 32; m; m >>= 1) {
        int ad = (lane ^ m) << 2;
        float t[NS];
#pragma unroll
        for (int s = 0; s < NS; ++s) t[s] = bperm(ad, acc[s]);
#pragma unroll
        for (int s = 0; s < NS; ++s) acc[s] += t[s];
    }

    float v0r[NS], v0i[NS], v1r[NS], v1i[NS];
#pragma unroll
    for (int s = 0; s < NS; ++s) {
        float rn = rsqrtf(acc[s]);
        v0r[s] = xv[s] * rn;
        v0i[s] = 0.f;
        v1r[s] = 0.f;
        v1i[s] = 0.f;
    }

#define GAPPLY(gi)                                                        \
    {                                                                     \
        float ur = gc[(gi)*4 + 0], ui = gc[(gi)*4 + 1];                   \
        float vr = gc[(gi)*4 + 2], vi = gc[(gi)*4 + 3];                   \
        _Pragma("unroll") for (int s = 0; s < NS; ++s) {                  \
            float n0r = ur * v0r[s] - ui * v0i[s] - vr * v1r[s] - vi * v1i[s]; \
            float n0i = ur * v0i[s] + ui * v0r[s] + vi * v1r[s] - vr * v1i[s]; \
            float n1r = vr * v0r[s] - vi * v0i[s] + ur * v1r[s] + ui * v1i[s]; \
            float n1i = vr * v0i[s] + vi * v0r[s] + ur * v1i[s] - ui * v1r[s]; \
            v0r[s] = n0r; v0i[s] = n0i; v1r[s] = n1r; v1i[s] = n1i;       \
        }                                                                 \
    }

// slot <-> lane-bit 5 exchange: swap v0.hi-half with v1.lo-half
#define RP32()                                                            \
    {                                                                     \
        _Pragma("unroll") for (int s = 0; s < NS; ++s) {                  \
            asm("v_permlane32_swap_b32 %0, %1" : "+v"(v0r[s]), "+v"(v1r[s])); \
            asm("v_permlane32_swap_b32 %0, %1" : "+v"(v0i[s]), "+v"(v1i[s])); \
        }                                                                 \
    }

// slot <-> lane-bit 4 exchange: swap v0 rows 1,3 with v1 rows 0,2 (16-lane rows)
#define RP16()                                                            \
    {                                                                     \
        _Pragma("unroll") for (int s = 0; s < NS; ++s) {                  \
            asm("v_permlane16_swap_b32 %0, %1" : "+v"(v0r[s]), "+v"(v1r[s])); \
            asm("v_permlane16_swap_b32 %0, %1" : "+v"(v0i[s]), "+v"(v1i[s])); \
        }                                                                 \
    }

// slot <-> lane-bit exchange via bpermute (m <= 8)
#define RPB(m)                                                            \
    {                                                                     \
        bool hi = (lane & (m)) != 0;                                      \
        int ad = (lane ^ (m)) << 2;                                       \
        _Pragma("unroll") for (int s = 0; s < NS; ++s) {                  \
            float sr = hi ? v0r[s] : v1r[s];                              \
            float si = hi ? v0i[s] : v1i[s];                              \
            float rr = bperm(ad, sr);                                     \
            float ri = bperm(ad, si);                                     \
            v0r[s] = hi ? rr : v0r[s];                                    \
            v0i[s] = hi ? ri : v0i[s];                                    \
            v1r[s] = hi ? v1r[s] : rr;                                    \
            v1i[s] = hi ? v1i[s] : ri;                                    \
        }                                                                 \
    }

    // ---- layer 1 ----
    // gate q=0 (amp bit 6 in slot): a1 = 0, a0 real
    {
        float ur = gc[0], ui = gc[1], vr = gc[2], vi = gc[3];
#pragma unroll
        for (int s = 0; s < NS; ++s) {
            float xx = v0r[s];
            v0r[s] = ur * xx; v0i[s] = ui * xx;
            v1r[s] = vr * xx; v1i[s] = vi * xx;
        }
    }
    RP32();
    // gate q=1: slot = amp bit 5; slot-1 amps still all zero
    {
        float ur = gc[4], ui = gc[5], vr = gc[6], vi = gc[7];
#pragma unroll
        for (int s = 0; s < NS; ++s) {
            float x0r = v0r[s], x0i = v0i[s];
            v0r[s] = ur * x0r - ui * x0i; v0i[s] = ur * x0i + ui * x0r;
            v1r[s] = vr * x0r - vi * x0i; v1i[s] = vr * x0i + vi * x0r;
        }
    }
    RP16(); GAPPLY(2);
    RPB(8); GAPPLY(3);
    RPB(4); GAPPLY(4);
    RPB(2); GAPPLY(5);
    RPB(1); GAPPLY(6);

    // entangle diag: sign(popcount) — invariant under the bit permutation
    int kc = __popc(lane);
    float s0 = ((kc >> 1) & 1) ? -1.f : 1.f;
    float s1 = (((kc + 1) >> 1) & 1) ? -1.f : 1.f;
#pragma unroll
    for (int s = 0; s < NS; ++s) {
        v0r[s] *= s0; v0i[s] *= s0; v1r[s] *= s1; v1i[s] *= s1;
    }

    // ---- layer 2 ----
    RP32(); GAPPLY(7);    // amp6
    RP16(); GAPPLY(8);    // amp5
    RPB(8); GAPPLY(9);    // amp4
    RPB(4); GAPPLY(10);   // amp3
    RPB(2); GAPPLY(11);   // amp2
    RPB(1); GAPPLY(12);   // amp1
    RP32(); GAPPLY(13);   // amp0
#pragma unroll
    for (int s = 0; s < NS; ++s) {
        v0r[s] *= s0; v0i[s] *= s0; v1r[s] *= s1; v1i[s] *= s1;
    }

    // measurement: z0 sign = -1 iff amp bit6 == 1; amp bit6 now on lane bit 4
    float e[NS];
#pragma unroll
    for (int s = 0; s < NS; ++s) {
        float t = v0r[s] * v0r[s] + v0i[s] * v0i[s] + v1r[s] * v1r[s] + v1i[s] * v1i[s];
        e[s] = (lane & 16) ? -t : t;
    }
#pragma unroll
    for (int m = 32; m; m >>= 1) {
        int ad = (lane ^ m) << 2;
        float t[NS];
#pragma unroll
        for (int s = 0; s < NS; ++s) t[s] = bperm(ad, e[s]);
#pragma unroll
        for (int s = 0; s < NS; ++s) e[s] += t[s];
    }
    if (lane == 0) {
#pragma unroll
        for (int s = 0; s < NS; ++s)
            out[(bidx[s] * 8 + oc) * L_OUT + lidx[s]] = e[s];
    }
#undef GAPPLY
#undef RP32
#undef RP16
#undef RPB
}

extern "C" void kernel_launch(void* const* d_in, const int* in_sizes, int n_in,
                              void* d_out, int out_size, void* d_ws, size_t ws_size,
                              hipStream_t stream) {
    const float* x = (const float*)d_in[0];
    const float* thetas = (const float*)d_in[1];
    float* out = (float*)d_out;

    if (ws_size >= 112 * 4 * sizeof(float)) {
        float* gates = (float*)d_ws;
        prep_gates_k<<<1, 128, 0, stream>>>(thetas, gates);
        qconv_k<true><<<N_BLK, 512, 0, stream>>>(x, thetas, gates, out);
    } else {
        qconv_k<false><<<N_BLK, 512, 0, stream>>>(x, thetas, nullptr, out);
    }
}